// Round 10
// baseline (1320.032 us; speedup 1.0000x reference)
//
#include <hip/hip_runtime.h>

// InteractionBlock: N=50000 nodes, M=32 nbrs, HID=128, FILT=128, NBR=64
//  k0a: node_repr f32 -> bf16 table in d_ws
//  k0b: fw1,fw2 -> bf16 TRANSPOSED tables in d_ws (w1T[f][64k], w2T[h][128k])
//  k1 : fused filter MLP (bf16 MFMA, weights from GLOBAL/L1) + block-gather
//       message reduction -> msg (d_out)
//  k2a: u = silu(msg@uw1+ub1) -> bf16 u in d_ws (overwrites node table; k1 done)
//  k2b: out = u@uw2+ub2 -> d_out
//
// R9 -> R10 (diagnosis: 2 waves/SIMD (LDS-capped) with ~85% stall; LDS layouts
// all hit even-banks-only (4c+2g) conflicts (8.2M); masked half-line msg
// stores caused 4.8x write amplification):
//  * weights OUT of LDS -> global bf16 tables (48KB, L1/L2-resident, shared
//    chip-wide). Kills weight bank conflicts + 53KB LDS.
//  * ft tile f32 [16][132]: write banks 4(c+g) (2-way free), read banks 8k
//    per r-group (2-way free)
//  * LDS 34.8KB/block + __launch_bounds__(256,4) -> 4 blocks/CU, 16 waves/CU
//  * gathers in 2 batches of 16 regs (peak VGPR < 128)
//  * msg store via LDS bounce -> all-lane float2 coalesced 512B store
//
// MFMA layouts (gfx950 16x16, verified m89/m91): A/B x32: row/col=lane&15,
// k=(lane>>4)*8+j; _1k x16: k=(lane>>4)*4+j; C/D: col=lane&15, row=(lane>>4)*4+reg.
// Transposed GEMM2 (A=w2 frag, B=P): lane holds filter[m=c][hid=16ct+4g+q].

#define NN 50000
#define MM 32
#define HID 128
#define NBR 64

typedef __attribute__((ext_vector_type(4))) float f32x4;
typedef __attribute__((ext_vector_type(2))) float f32x2;
typedef __attribute__((ext_vector_type(8))) short s16x8;
typedef __attribute__((ext_vector_type(4))) short s16x4;

__device__ __forceinline__ short f2bf(float x) {
  unsigned u = __builtin_bit_cast(unsigned, x);
  unsigned r = (u + 0x7FFFu + ((u >> 16) & 1u)) >> 16;
  return (short)r;
}

__device__ __forceinline__ float bf2f(short b) {
  return __builtin_bit_cast(float, (unsigned)(unsigned short)b << 16);
}

__device__ __forceinline__ float silu(float x) {
  return x / (1.0f + __expf(-x));
}

// ---------------------------------------------------------------- kernel 0a
__global__ __launch_bounds__(256) void k_cvt_node(
    const float* __restrict__ in, short* __restrict__ out)
{
  int i = blockIdx.x * 256 + threadIdx.x;            // float4 index
  if (i < NN * HID / 4) {
    f32x4 v = *(reinterpret_cast<const f32x4*>(in) + i);
    s16x4 o;
    #pragma unroll
    for (int r = 0; r < 4; ++r) o[r] = f2bf(v[r]);
    reinterpret_cast<s16x4*>(out)[i] = o;
  }
}

// ---------------------------------------------------------------- kernel 0b
// fw1 [64k][128f] -> w1T bf16 [f][64k]; fw2 [128k][128h] -> w2T bf16 [h][128k]
__global__ __launch_bounds__(256) void k_cvt_w(
    const float* __restrict__ fw1, const float* __restrict__ fw2,
    short* __restrict__ w1T, short* __restrict__ w2T)
{
  int tid = blockIdx.x * 256 + threadIdx.x;
  int stride = gridDim.x * 256;
  for (int i = tid; i < 64 * 128; i += stride) {
    int k = i >> 7, f = i & 127;
    w1T[f * 64 + k] = f2bf(fw1[i]);
  }
  for (int i = tid; i < 128 * 128; i += stride) {
    int k = i >> 7, h = i & 127;
    w2T[h * 128 + k] = f2bf(fw2[i]);
  }
}

// ---------------------------------------------------------------- kernel 1
__global__ __launch_bounds__(256, 4) void k_filter_message(
    const short* __restrict__ node_bf, const float* __restrict__ nbr_fea,
    const int* __restrict__ nbr_idx, const short* __restrict__ w1T,
    const short* __restrict__ w2T, const float* __restrict__ fb1,
    const float* __restrict__ fb2, float* __restrict__ msg_out)
{
  __shared__ float s_b1[128];
  __shared__ __align__(16) float s_b2[128];
  __shared__ __align__(16) float s_ft[4][16 * 132];  // per-wave f32 filter tile, 33.8KB
  // total 34.8KB -> 4 blocks/CU

  const int tid = threadIdx.x;
  if (tid < 128) { s_b1[tid] = fb1[tid]; s_b2[tid] = fb2[tid]; }
  __syncthreads();

  const int wave = tid >> 6, lane = tid & 63;
  const int c = lane & 15, g = lane >> 4;     // MFMA fragment coords
  const int r = lane >> 3, k = lane & 7;      // block-gather coords
  float* __restrict__ ft = s_ft[wave];        // wave-private [16 rows][132]
  const int gw = blockIdx.x * 4 + wave;
  const int STRIDE = 1024 * 4;                // 4096 waves

  // prologue: this node's gather row indices (rows mt*16+8i+r)
  int vidx[2][2];
  #pragma unroll
  for (int mt = 0; mt < 2; ++mt)
    #pragma unroll
    for (int i = 0; i < 2; ++i)
      vidx[mt][i] = nbr_idx[(size_t)gw * MM + mt * 16 + 8 * i + r];

  for (int n = gw; n < NN; n += STRIDE) {
    // 1: batch-A gathers (mt=0): lane (r,k) reads row vidx[0][i], 16B chunks
    s16x8 gr0[2][2];   // [i][h]
    #pragma unroll
    for (int i = 0; i < 2; ++i) {
      const short* rp = node_bf + (size_t)vidx[0][i] * HID + 8 * k;
      gr0[i][0] = *reinterpret_cast<const s16x8*>(rp);
      gr0[i][1] = *reinterpret_cast<const s16x8*>(rp + 64);
    }

    // 2: stream nbr_fea (NT) -> B1 frags
    const float* nf = nbr_fea + (size_t)n * (MM * NBR);
    s16x8 b1[2][2];
    #pragma unroll
    for (int mt = 0; mt < 2; ++mt)
      #pragma unroll
      for (int kt = 0; kt < 2; ++kt) {
        const f32x4* src = reinterpret_cast<const f32x4*>(
            nf + (mt * 16 + c) * NBR + kt * 32 + g * 8);
        f32x4 lo = __builtin_nontemporal_load(src);
        f32x4 hi = __builtin_nontemporal_load(src + 1);
        s16x8 v;
        v[0] = f2bf(lo[0]); v[1] = f2bf(lo[1]); v[2] = f2bf(lo[2]); v[3] = f2bf(lo[3]);
        v[4] = f2bf(hi[0]); v[5] = f2bf(hi[1]); v[6] = f2bf(hi[2]); v[7] = f2bf(hi[3]);
        b1[mt][kt] = v;
      }

    // 3: GEMM1 (transposed): h^T = fw1T . nbr^T (16x16x32), w1 frags from L1
    s16x4 P[8][2];
    #pragma unroll
    for (int t = 0; t < 8; ++t) {
      f32x4 a0 = f32x4{0.f, 0.f, 0.f, 0.f};
      f32x4 a1 = f32x4{0.f, 0.f, 0.f, 0.f};
      #pragma unroll
      for (int kt = 0; kt < 2; ++kt) {
        s16x8 w1f = *reinterpret_cast<const s16x8*>(
            w1T + (t * 16 + c) * 64 + kt * 32 + g * 8);
        a0 = __builtin_amdgcn_mfma_f32_16x16x32_bf16(w1f, b1[0][kt], a0, 0, 0, 0);
        a1 = __builtin_amdgcn_mfma_f32_16x16x32_bf16(w1f, b1[1][kt], a1, 0, 0, 0);
      }
      s16x4 p0, p1;
      #pragma unroll
      for (int q = 0; q < 4; ++q) {
        float bias = s_b1[t * 16 + g * 4 + q];
        p0[q] = f2bf(silu(a0[q] + bias));
        p1[q] = f2bf(silu(a1[q] + bias));
      }
      P[t][0] = p0;
      P[t][1] = p1;
    }

    // 4: batch-B gathers (mt=1) — covered by GEMM2 mt=0 + FMA mt=0
    s16x8 gr1[2][2];
    #pragma unroll
    for (int i = 0; i < 2; ++i) {
      const short* rp = node_bf + (size_t)vidx[1][i] * HID + 8 * k;
      gr1[i][0] = *reinterpret_cast<const s16x8*>(rp);
      gr1[i][1] = *reinterpret_cast<const s16x8*>(rp + 64);
    }

    // 5: prefetch NEXT node's gather indices
    {
      int n2 = n + STRIDE;
      int np = (n2 < NN) ? n2 : n;
      #pragma unroll
      for (int mt = 0; mt < 2; ++mt)
        #pragma unroll
        for (int i = 0; i < 2; ++i)
          vidx[mt][i] = nbr_idx[(size_t)np * MM + mt * 16 + 8 * i + r];
    }

    // 6: per mt-half: GEMM2 (transposed, w2 frags from L1) -> f32 ft tile ->
    //    block-gather FMA
    float part0[8], part1[8];   // partial msg, hid = 64h + 8k + j
    #pragma unroll
    for (int j = 0; j < 8; ++j) { part0[j] = 0.f; part1[j] = 0.f; }

    #pragma unroll
    for (int mt = 0; mt < 2; ++mt) {
      #pragma unroll
      for (int ct = 0; ct < 8; ++ct) {
        f32x4 t = f32x4{0.f, 0.f, 0.f, 0.f};
        #pragma unroll
        for (int kt = 0; kt < 8; ++kt) {
          s16x4 w2f = *reinterpret_cast<const s16x4*>(
              w2T + (ct * 16 + c) * 128 + kt * 16 + g * 4);
          t = __builtin_amdgcn_mfma_f32_16x16x16bf16_1k(w2f, P[kt][mt], t, 0, 0, 0);
        }
        f32x4 fb = *reinterpret_cast<const f32x4*>(&s_b2[ct * 16 + 4 * g]);
        f32x4 o;
        #pragma unroll
        for (int q = 0; q < 4; ++q) o[q] = t[q] + fb[q];
        // lane holds filter[m=c][hid=16ct+4g+q] -> ft row c (f32, bank-clean)
        *reinterpret_cast<f32x4*>(&ft[c * 132 + ct * 16 + 4 * g]) = o;
      }
      // block-gather FMA: lane (r,k) reads tile rows 8i+r, f32 chunk k
      #pragma unroll
      for (int i = 0; i < 2; ++i) {
        const s16x8 ga = (mt == 0) ? gr0[i][0] : gr1[i][0];
        const s16x8 gb = (mt == 0) ? gr0[i][1] : gr1[i][1];
        f32x4 fa0 = *reinterpret_cast<const f32x4*>(&ft[(8 * i + r) * 132 + 8 * k]);
        f32x4 fa1 = *reinterpret_cast<const f32x4*>(&ft[(8 * i + r) * 132 + 8 * k + 4]);
        f32x4 fb0 = *reinterpret_cast<const f32x4*>(&ft[(8 * i + r) * 132 + 64 + 8 * k]);
        f32x4 fb1 = *reinterpret_cast<const f32x4*>(&ft[(8 * i + r) * 132 + 64 + 8 * k + 4]);
        #pragma unroll
        for (int j = 0; j < 4; ++j) {
          part0[j]     += fa0[j] * bf2f(ga[j]);
          part0[j + 4] += fa1[j] * bf2f(ga[j + 4]);
          part1[j]     += fb0[j] * bf2f(gb[j]);
          part1[j + 4] += fb1[j] * bf2f(gb[j + 4]);
        }
      }
    }

    // 7: reduce over r (stride-8 lanes)
    #pragma unroll
    for (int j = 0; j < 8; ++j) {
      part0[j] += __shfl_xor(part0[j], 8);
      part0[j] += __shfl_xor(part0[j], 16);
      part0[j] += __shfl_xor(part0[j], 32);
      part1[j] += __shfl_xor(part1[j], 8);
      part1[j] += __shfl_xor(part1[j], 16);
      part1[j] += __shfl_xor(part1[j], 32);
    }

    // 8: store via LDS bounce (reuse ft row 0 region): r==0 lanes deposit,
    //    then all 64 lanes store float2 -> one 512B fully-coalesced line set
    if (r == 0) {
      *reinterpret_cast<f32x4*>(&ft[8 * k])          = f32x4{part0[0], part0[1], part0[2], part0[3]};
      *reinterpret_cast<f32x4*>(&ft[8 * k + 4])      = f32x4{part0[4], part0[5], part0[6], part0[7]};
      *reinterpret_cast<f32x4*>(&ft[64 + 8 * k])     = f32x4{part1[0], part1[1], part1[2], part1[3]};
      *reinterpret_cast<f32x4*>(&ft[64 + 8 * k + 4]) = f32x4{part1[4], part1[5], part1[6], part1[7]};
    }
    f32x2 mv = *reinterpret_cast<const f32x2*>(&ft[2 * lane]);
    *reinterpret_cast<f32x2*>(msg_out + (size_t)n * HID + 2 * lane) = mv;
  }
}

// ---------------------------------------------------------------- kernel 2a
// u^T = silu(uw1^T . msg^T + ub1) -> bf16 u[row][128] in ws
__global__ __launch_bounds__(256, 2) void k_update1(
    const float* __restrict__ msg, const float* __restrict__ uw1,
    const float* __restrict__ ub1, short* __restrict__ u_out)
{
  __shared__ __align__(16) short s_w1[128 * 136];   // uw1T[f][k], stride 136
  __shared__ float s_b1[128];
  const int tid = threadIdx.x;
  for (int i = tid; i < 128 * 128; i += 256) {      // uw1 given [k][f]
    int k = i >> 7, f = i & 127;
    s_w1[f * 136 + k] = f2bf(uw1[i]);
  }
  if (tid < 128) s_b1[tid] = ub1[tid];
  __syncthreads();

  const int wave = tid >> 6, lane = tid & 63;
  const int c = lane & 15, g = lane >> 4;
  const long base = (long)(blockIdx.x * 4 + wave) * 32;
  if (base >= NN) return;

  s16x8 bfr[2][4];
  #pragma unroll
  for (int mt = 0; mt < 2; ++mt)
    #pragma unroll
    for (int kt = 0; kt < 4; ++kt) {
      long row = base + mt * 16 + c; if (row > NN - 1) row = NN - 1;
      const float* src = msg + row * HID + kt * 32 + g * 8;
      float4 lo = *reinterpret_cast<const float4*>(src);
      float4 hi = *reinterpret_cast<const float4*>(src + 4);
      s16x8 v;
      v[0] = f2bf(lo.x); v[1] = f2bf(lo.y); v[2] = f2bf(lo.z); v[3] = f2bf(lo.w);
      v[4] = f2bf(hi.x); v[5] = f2bf(hi.y); v[6] = f2bf(hi.z); v[7] = f2bf(hi.w);
      bfr[mt][kt] = v;
    }

  f32x4 acc[8][2];
  #pragma unroll
  for (int t = 0; t < 8; ++t)
    #pragma unroll
    for (int mt = 0; mt < 2; ++mt)
      acc[t][mt] = f32x4{0.f, 0.f, 0.f, 0.f};
  #pragma unroll
  for (int kt = 0; kt < 4; ++kt)
    #pragma unroll
    for (int t = 0; t < 8; ++t) {
      s16x8 a = *reinterpret_cast<const s16x8*>(&s_w1[(t * 16 + c) * 136 + kt * 32 + g * 8]);
      #pragma unroll
      for (int mt = 0; mt < 2; ++mt)
        acc[t][mt] = __builtin_amdgcn_mfma_f32_16x16x32_bf16(a, bfr[mt][kt], acc[t][mt], 0, 0, 0);
    }

  #pragma unroll
  for (int t = 0; t < 8; ++t)
    #pragma unroll
    for (int mt = 0; mt < 2; ++mt) {
      long row = base + mt * 16 + c;
      if (row < NN) {
        s16x4 p;
        #pragma unroll
        for (int q = 0; q < 4; ++q) {
          float x = acc[t][mt][q] + s_b1[t * 16 + g * 4 + q];
          p[q] = f2bf(silu(x));
        }
        *reinterpret_cast<s16x4*>(&u_out[row * HID + t * 16 + g * 4]) = p;
      }
    }
}

// ---------------------------------------------------------------- kernel 2b
// out[m][hid] = u . uw2 + ub2   (16x16x16, A from bf16 u in ws)
__global__ __launch_bounds__(256, 2) void k_update2(
    const short* __restrict__ u, const float* __restrict__ uw2,
    const float* __restrict__ ub2, float* __restrict__ out)
{
  __shared__ __align__(16) short s_w2[128 * 136];   // uw2T[h][k]
  __shared__ float s_b2[128];
  const int tid = threadIdx.x;
  for (int i = tid; i < 128 * 128; i += 256) {      // uw2 given [k][h]
    int k = i >> 7, h = i & 127;
    s_w2[h * 136 + k] = f2bf(uw2[i]);
  }
  if (tid < 128) s_b2[tid] = ub2[tid];
  __syncthreads();

  const int wave = tid >> 6, lane = tid & 63;
  const int c = lane & 15, g = lane >> 4;
  const long base = (long)(blockIdx.x * 4 + wave) * 32;
  if (base >= NN) return;

  s16x4 afr[2][8];
  #pragma unroll
  for (int mt = 0; mt < 2; ++mt)
    #pragma unroll
    for (int kt = 0; kt < 8; ++kt) {
      long row = base + mt * 16 + c; if (row > NN - 1) row = NN - 1;
      afr[mt][kt] = *reinterpret_cast<const s16x4*>(&u[row * HID + kt * 16 + g * 4]);
    }

  f32x4 acc[8][2];
  #pragma unroll
  for (int ct = 0; ct < 8; ++ct)
    #pragma unroll
    for (int mt = 0; mt < 2; ++mt)
      acc[ct][mt] = f32x4{0.f, 0.f, 0.f, 0.f};
  #pragma unroll
  for (int ct = 0; ct < 8; ++ct)
    #pragma unroll
    for (int kt = 0; kt < 8; ++kt) {
      s16x4 b2 = *reinterpret_cast<const s16x4*>(&s_w2[(ct * 16 + c) * 136 + kt * 16 + g * 4]);
      #pragma unroll
      for (int mt = 0; mt < 2; ++mt)
        acc[ct][mt] = __builtin_amdgcn_mfma_f32_16x16x16bf16_1k(afr[mt][kt], b2, acc[ct][mt], 0, 0, 0);
    }

  #pragma unroll
  for (int ct = 0; ct < 8; ++ct) {
    const float bias = s_b2[ct * 16 + c];
    #pragma unroll
    for (int mt = 0; mt < 2; ++mt)
      #pragma unroll
      for (int q = 0; q < 4; ++q) {
        long row = base + mt * 16 + g * 4 + q;
        if (row < NN) out[row * HID + ct * 16 + c] = acc[ct][mt][q] + bias;
      }
  }
}

// ---------------------------------------------------------------- launch
extern "C" void kernel_launch(void* const* d_in, const int* in_sizes, int n_in,
                              void* d_out, int out_size, void* d_ws, size_t ws_size,
                              hipStream_t stream) {
  const float* node_repr = (const float*)d_in[0];
  const float* nbr_fea   = (const float*)d_in[1];
  const int*   nbr_idx   = (const int*)d_in[2];
  const float* fw1 = (const float*)d_in[3];
  const float* fb1 = (const float*)d_in[4];
  const float* fw2 = (const float*)d_in[5];
  const float* fb2 = (const float*)d_in[6];
  const float* uw1 = (const float*)d_in[7];
  const float* ub1 = (const float*)d_in[8];
  const float* uw2 = (const float*)d_in[9];
  const float* ub2 = (const float*)d_in[10];
  float* outp = (float*)d_out;
  short* ws16 = (short*)d_ws;
  // ws layout: [0, 6.4M shorts) node_bf16 (later overwritten by u in k2a);
  //            [6.4M, +8192) w1T bf16; [+8192, +16384) w2T bf16
  short* w1T = ws16 + (size_t)NN * HID;
  short* w2T = w1T + 64 * 128;

  k_cvt_node<<<(NN * HID / 4 + 255) / 256, 256, 0, stream>>>(node_repr, ws16);
  k_cvt_w<<<32, 256, 0, stream>>>(fw1, fw2, w1T, w2T);
  // k1: 1024 blocks x 256 thr, 4 blocks/CU (LDS 34.8KB, VGPR<=128), 16 waves/CU
  k_filter_message<<<1024, 256, 0, stream>>>(ws16, nbr_fea, nbr_idx,
                                             w1T, w2T, fb1, fb2, outp);
  const int rowblocks = (NN + 31) / 32;        // 1563
  const int grid2 = (rowblocks + 3) / 4;       // 391
  k_update1<<<grid2, 256, 0, stream>>>(outp, uw1, ub1, ws16);  // u overwrites node_bf16
  k_update2<<<grid2, 256, 0, stream>>>(ws16, uw2, ub2, outp);
}

// Round 11
// 754.281 us; speedup vs baseline: 1.7501x; 1.7501x over previous
//
#include <hip/hip_runtime.h>

// InteractionBlock: N=50000 nodes, M=32 nbrs, HID=128, FILT=128, NBR=64
//  k0a: node_repr f32 -> bf16 table in d_ws
//  k0b: fw1,fw2 -> bf16 transposed tables in d_ws
//  k1 : PAIR-SPLIT fused filter MLP + block-gather message -> msg (d_out)
//  k2a: u = silu(msg@uw1+ub1) -> bf16 u in d_ws (overwrites node table)
//  k2b: out = u@uw2+ub2 -> d_out
//
// R10 -> R11 (diagnosis: (256,4) cap=128 regs vs natural ~190 -> 100-reg spill,
// WRITE 1.05GB of scratch; occupancy rose but drowned):
//  * PAIR-SPLIT: waves (2p,2p+1) share node n0+p, each owns neighbor-half
//    mt=wave&1. Per-wave: b1 8, P 16, gathers 16, part 16 -> natural ~90 regs
//    -> genuinely fits 4 waves/SIMD under (256,4), no spills.
//  * halves combine via 1KB LDS pair-buffer: half0 deposits, barrier, half1
//    adds + all-64-lane coalesced 512B store (keeps R10 write-amp fix).
//  * ft tile bf16 [16][136] (R9-proven): LDS 19.5KB/block.
//  * weights stay in GLOBAL bf16 tables (R10's sound part — L1/L2-resident).
//
// MFMA layouts (gfx950 16x16, verified m89/m91): A/B x32: row/col=lane&15,
// k=(lane>>4)*8+j; _1k x16: k=(lane>>4)*4+j; C/D: col=lane&15, row=(lane>>4)*4+reg.
// Transposed GEMM2 (A=w2 frag, B=P): lane holds filter[m=c][hid=16ct+4g+q].

#define NN 50000
#define MM 32
#define HID 128
#define NBR 64

typedef __attribute__((ext_vector_type(4))) float f32x4;
typedef __attribute__((ext_vector_type(2))) float f32x2;
typedef __attribute__((ext_vector_type(8))) short s16x8;
typedef __attribute__((ext_vector_type(4))) short s16x4;

__device__ __forceinline__ short f2bf(float x) {
  unsigned u = __builtin_bit_cast(unsigned, x);
  unsigned r = (u + 0x7FFFu + ((u >> 16) & 1u)) >> 16;
  return (short)r;
}

__device__ __forceinline__ float bf2f(short b) {
  return __builtin_bit_cast(float, (unsigned)(unsigned short)b << 16);
}

__device__ __forceinline__ float silu(float x) {
  return x / (1.0f + __expf(-x));
}

// ---------------------------------------------------------------- kernel 0a
__global__ __launch_bounds__(256) void k_cvt_node(
    const float* __restrict__ in, short* __restrict__ out)
{
  int i = blockIdx.x * 256 + threadIdx.x;            // float4 index
  if (i < NN * HID / 4) {
    f32x4 v = *(reinterpret_cast<const f32x4*>(in) + i);
    s16x4 o;
    #pragma unroll
    for (int r = 0; r < 4; ++r) o[r] = f2bf(v[r]);
    reinterpret_cast<s16x4*>(out)[i] = o;
  }
}

// ---------------------------------------------------------------- kernel 0b
// fw1 [64k][128f] -> w1T bf16 [f][64k]; fw2 [128k][128h] -> w2T bf16 [h][128k]
__global__ __launch_bounds__(256) void k_cvt_w(
    const float* __restrict__ fw1, const float* __restrict__ fw2,
    short* __restrict__ w1T, short* __restrict__ w2T)
{
  int tid = blockIdx.x * 256 + threadIdx.x;
  int stride = gridDim.x * 256;
  for (int i = tid; i < 64 * 128; i += stride) {
    int k = i >> 7, f = i & 127;
    w1T[f * 64 + k] = f2bf(fw1[i]);
  }
  for (int i = tid; i < 128 * 128; i += stride) {
    int k = i >> 7, h = i & 127;
    w2T[h * 128 + k] = f2bf(fw2[i]);
  }
}

// ---------------------------------------------------------------- kernel 1
__global__ __launch_bounds__(256, 4) void k_filter_message(
    const short* __restrict__ node_bf, const float* __restrict__ nbr_fea,
    const int* __restrict__ nbr_idx, const short* __restrict__ w1T,
    const short* __restrict__ w2T, const float* __restrict__ fb1,
    const float* __restrict__ fb2, float* __restrict__ msg_out)
{
  __shared__ float s_b1[128];
  __shared__ __align__(16) float s_b2[128];
  __shared__ __align__(16) short s_ft[4][16 * 136];  // per-wave bf16 filter tile, 17.4KB
  __shared__ __align__(16) float s_pair[2][128];     // pair combine buffer, 1KB
  // total ~19.5KB/block

  const int tid = threadIdx.x;
  if (tid < 128) { s_b1[tid] = fb1[tid]; s_b2[tid] = fb2[tid]; }
  __syncthreads();

  const int wave = tid >> 6, lane = tid & 63;
  const int c = lane & 15, g = lane >> 4;     // MFMA fragment coords
  const int r = lane >> 3, k = lane & 7;      // block-gather coords
  const int p = wave >> 1, half = wave & 1;   // pair id, neighbor-half (mt)
  short* __restrict__ ft = s_ft[wave];        // wave-private [16 rows][136]
  float* __restrict__ pb = s_pair[p];         // pair-shared [128]
  const int STRIDE = 1024 * 2;                // grid 1024 blocks, 2 nodes/block

  // prologue: first node's gather indices (rows m = half*16 + 8i + r)
  int vidx[2];
  {
    const int n = blockIdx.x * 2 + p;
    vidx[0] = nbr_idx[(size_t)n * MM + half * 16 + r];
    vidx[1] = nbr_idx[(size_t)n * MM + half * 16 + 8 + r];
  }

  for (int n0 = blockIdx.x * 2; n0 < NN; n0 += STRIDE) {
    const int n = n0 + p;   // this pair's node (NN even -> always valid)

    // 1: block-gathers for this half (16 regs): lane (r,k) reads row vidx[i]
    s16x8 gr[2][2];   // [i][h]
    #pragma unroll
    for (int i = 0; i < 2; ++i) {
      const short* rp = node_bf + (size_t)vidx[i] * HID + 8 * k;
      gr[i][0] = *reinterpret_cast<const s16x8*>(rp);
      gr[i][1] = *reinterpret_cast<const s16x8*>(rp + 64);
    }

    // 2: stream this half's nbr_fea rows (NT) -> B1 frags (8 regs)
    const float* nf = nbr_fea + (size_t)n * (MM * NBR);
    s16x8 b1[2];
    #pragma unroll
    for (int kt = 0; kt < 2; ++kt) {
      const f32x4* src = reinterpret_cast<const f32x4*>(
          nf + (half * 16 + c) * NBR + kt * 32 + g * 8);
      f32x4 lo = __builtin_nontemporal_load(src);
      f32x4 hi = __builtin_nontemporal_load(src + 1);
      s16x8 v;
      v[0] = f2bf(lo[0]); v[1] = f2bf(lo[1]); v[2] = f2bf(lo[2]); v[3] = f2bf(lo[3]);
      v[4] = f2bf(hi[0]); v[5] = f2bf(hi[1]); v[6] = f2bf(hi[2]); v[7] = f2bf(hi[3]);
      b1[kt] = v;
    }

    // 3: prefetch NEXT node's gather indices
    {
      int n2 = n0 + STRIDE;
      int np = (n2 < NN) ? (n2 + p) : n;
      vidx[0] = nbr_idx[(size_t)np * MM + half * 16 + r];
      vidx[1] = nbr_idx[(size_t)np * MM + half * 16 + 8 + r];
    }

    // 4: GEMM1 (transposed): h^T = fw1T . nbr^T (w1 frags from L1) -> P
    s16x4 P[8];
    #pragma unroll
    for (int t = 0; t < 8; ++t) {
      f32x4 a = f32x4{0.f, 0.f, 0.f, 0.f};
      #pragma unroll
      for (int kt = 0; kt < 2; ++kt) {
        s16x8 w1f = *reinterpret_cast<const s16x8*>(
            w1T + (t * 16 + c) * 64 + kt * 32 + g * 8);
        a = __builtin_amdgcn_mfma_f32_16x16x32_bf16(w1f, b1[kt], a, 0, 0, 0);
      }
      s16x4 pk;
      #pragma unroll
      for (int q = 0; q < 4; ++q)
        pk[q] = f2bf(silu(a[q] + s_b1[t * 16 + g * 4 + q]));
      P[t] = pk;
    }

    // 5: GEMM2 (transposed, w2 frags from L1) -> bf16 ft tile
    #pragma unroll
    for (int ct = 0; ct < 8; ++ct) {
      f32x4 t = f32x4{0.f, 0.f, 0.f, 0.f};
      #pragma unroll
      for (int kt = 0; kt < 8; ++kt) {
        s16x4 w2f = *reinterpret_cast<const s16x4*>(
            w2T + (ct * 16 + c) * 128 + kt * 16 + g * 4);
        t = __builtin_amdgcn_mfma_f32_16x16x16bf16_1k(w2f, P[kt], t, 0, 0, 0);
      }
      f32x4 fb = *reinterpret_cast<const f32x4*>(&s_b2[ct * 16 + 4 * g]);
      s16x4 pk;
      #pragma unroll
      for (int q = 0; q < 4; ++q) pk[q] = f2bf(t[q] + fb[q]);
      // lane holds filter[m=half*16+c][hid=16ct+4g+q] -> tile row c
      *reinterpret_cast<s16x4*>(&ft[c * 136 + ct * 16 + 4 * g]) = pk;
    }

    // 6: block-gather FMA: lane (r,k) reads tile rows 8i+r, chunk k
    float part0[8], part1[8];   // partial msg, hid = 8k+j and 64+8k+j
    #pragma unroll
    for (int j = 0; j < 8; ++j) { part0[j] = 0.f; part1[j] = 0.f; }
    #pragma unroll
    for (int i = 0; i < 2; ++i) {
      s16x8 f0 = *reinterpret_cast<const s16x8*>(&ft[(8 * i + r) * 136 + 8 * k]);
      s16x8 f1 = *reinterpret_cast<const s16x8*>(&ft[(8 * i + r) * 136 + 64 + 8 * k]);
      #pragma unroll
      for (int j = 0; j < 8; ++j) {
        part0[j] += bf2f(f0[j]) * bf2f(gr[i][0][j]);
        part1[j] += bf2f(f1[j]) * bf2f(gr[i][1][j]);
      }
    }

    // 7: reduce over r (stride-8 lanes); all lanes end with the group sum
    #pragma unroll
    for (int j = 0; j < 8; ++j) {
      part0[j] += __shfl_xor(part0[j], 8);
      part0[j] += __shfl_xor(part0[j], 16);
      part0[j] += __shfl_xor(part0[j], 32);
      part1[j] += __shfl_xor(part1[j], 8);
      part1[j] += __shfl_xor(part1[j], 16);
      part1[j] += __shfl_xor(part1[j], 32);
    }

    // 8: combine halves via pair buffer; half1 does the coalesced store
    if (half == 0 && r == 0) {
      *reinterpret_cast<f32x4*>(&pb[8 * k])          = f32x4{part0[0], part0[1], part0[2], part0[3]};
      *reinterpret_cast<f32x4*>(&pb[8 * k + 4])      = f32x4{part0[4], part0[5], part0[6], part0[7]};
      *reinterpret_cast<f32x4*>(&pb[64 + 8 * k])     = f32x4{part1[0], part1[1], part1[2], part1[3]};
      *reinterpret_cast<f32x4*>(&pb[64 + 8 * k + 4]) = f32x4{part1[4], part1[5], part1[6], part1[7]};
    }
    __syncthreads();
    if (half == 1) {
      if (r == 0) {
        f32x4 a0 = *reinterpret_cast<const f32x4*>(&pb[8 * k]);
        f32x4 a1 = *reinterpret_cast<const f32x4*>(&pb[8 * k + 4]);
        f32x4 a2 = *reinterpret_cast<const f32x4*>(&pb[64 + 8 * k]);
        f32x4 a3 = *reinterpret_cast<const f32x4*>(&pb[64 + 8 * k + 4]);
        #pragma unroll
        for (int j = 0; j < 4; ++j) {
          a0[j] += part0[j]; a1[j] += part0[j + 4];
          a2[j] += part1[j]; a3[j] += part1[j + 4];
        }
        *reinterpret_cast<f32x4*>(&pb[8 * k])          = a0;
        *reinterpret_cast<f32x4*>(&pb[8 * k + 4])      = a1;
        *reinterpret_cast<f32x4*>(&pb[64 + 8 * k])     = a2;
        *reinterpret_cast<f32x4*>(&pb[64 + 8 * k + 4]) = a3;
      }
      // same-wave LDS ordering (compiler lgkmcnt); all 64 lanes store 512B
      f32x2 mv = *reinterpret_cast<const f32x2*>(&pb[2 * lane]);
      *reinterpret_cast<f32x2*>(msg_out + (size_t)n * HID + 2 * lane) = mv;
    }
    __syncthreads();   // protect pair buffer before next iteration's deposit
  }
}

// ---------------------------------------------------------------- kernel 2a
// u^T = silu(uw1^T . msg^T + ub1) -> bf16 u[row][128] in ws
__global__ __launch_bounds__(256, 2) void k_update1(
    const float* __restrict__ msg, const float* __restrict__ uw1,
    const float* __restrict__ ub1, short* __restrict__ u_out)
{
  __shared__ __align__(16) short s_w1[128 * 136];   // uw1T[f][k], stride 136
  __shared__ float s_b1[128];
  const int tid = threadIdx.x;
  for (int i = tid; i < 128 * 128; i += 256) {      // uw1 given [k][f]
    int k = i >> 7, f = i & 127;
    s_w1[f * 136 + k] = f2bf(uw1[i]);
  }
  if (tid < 128) s_b1[tid] = ub1[tid];
  __syncthreads();

  const int wave = tid >> 6, lane = tid & 63;
  const int c = lane & 15, g = lane >> 4;
  const long base = (long)(blockIdx.x * 4 + wave) * 32;
  if (base >= NN) return;

  s16x8 bfr[2][4];
  #pragma unroll
  for (int mt = 0; mt < 2; ++mt)
    #pragma unroll
    for (int kt = 0; kt < 4; ++kt) {
      long row = base + mt * 16 + c; if (row > NN - 1) row = NN - 1;
      const float* src = msg + row * HID + kt * 32 + g * 8;
      float4 lo = *reinterpret_cast<const float4*>(src);
      float4 hi = *reinterpret_cast<const float4*>(src + 4);
      s16x8 v;
      v[0] = f2bf(lo.x); v[1] = f2bf(lo.y); v[2] = f2bf(lo.z); v[3] = f2bf(lo.w);
      v[4] = f2bf(hi.x); v[5] = f2bf(hi.y); v[6] = f2bf(hi.z); v[7] = f2bf(hi.w);
      bfr[mt][kt] = v;
    }

  f32x4 acc[8][2];
  #pragma unroll
  for (int t = 0; t < 8; ++t)
    #pragma unroll
    for (int mt = 0; mt < 2; ++mt)
      acc[t][mt] = f32x4{0.f, 0.f, 0.f, 0.f};
  #pragma unroll
  for (int kt = 0; kt < 4; ++kt)
    #pragma unroll
    for (int t = 0; t < 8; ++t) {
      s16x8 a = *reinterpret_cast<const s16x8*>(&s_w1[(t * 16 + c) * 136 + kt * 32 + g * 8]);
      #pragma unroll
      for (int mt = 0; mt < 2; ++mt)
        acc[t][mt] = __builtin_amdgcn_mfma_f32_16x16x32_bf16(a, bfr[mt][kt], acc[t][mt], 0, 0, 0);
    }

  #pragma unroll
  for (int t = 0; t < 8; ++t)
    #pragma unroll
    for (int mt = 0; mt < 2; ++mt) {
      long row = base + mt * 16 + c;
      if (row < NN) {
        s16x4 p;
        #pragma unroll
        for (int q = 0; q < 4; ++q) {
          float x = acc[t][mt][q] + s_b1[t * 16 + g * 4 + q];
          p[q] = f2bf(silu(x));
        }
        *reinterpret_cast<s16x4*>(&u_out[row * HID + t * 16 + g * 4]) = p;
      }
    }
}

// ---------------------------------------------------------------- kernel 2b
// out[m][hid] = u . uw2 + ub2   (16x16x16, A from bf16 u in ws)
__global__ __launch_bounds__(256, 2) void k_update2(
    const short* __restrict__ u, const float* __restrict__ uw2,
    const float* __restrict__ ub2, float* __restrict__ out)
{
  __shared__ __align__(16) short s_w2[128 * 136];   // uw2T[h][k]
  __shared__ float s_b2[128];
  const int tid = threadIdx.x;
  for (int i = tid; i < 128 * 128; i += 256) {      // uw2 given [k][h]
    int k = i >> 7, h = i & 127;
    s_w2[h * 136 + k] = f2bf(uw2[i]);
  }
  if (tid < 128) s_b2[tid] = ub2[tid];
  __syncthreads();

  const int wave = tid >> 6, lane = tid & 63;
  const int c = lane & 15, g = lane >> 4;
  const long base = (long)(blockIdx.x * 4 + wave) * 32;
  if (base >= NN) return;

  s16x4 afr[2][8];
  #pragma unroll
  for (int mt = 0; mt < 2; ++mt)
    #pragma unroll
    for (int kt = 0; kt < 8; ++kt) {
      long row = base + mt * 16 + c; if (row > NN - 1) row = NN - 1;
      afr[mt][kt] = *reinterpret_cast<const s16x4*>(&u[row * HID + kt * 16 + g * 4]);
    }

  f32x4 acc[8][2];
  #pragma unroll
  for (int ct = 0; ct < 8; ++ct)
    #pragma unroll
    for (int mt = 0; mt < 2; ++mt)
      acc[ct][mt] = f32x4{0.f, 0.f, 0.f, 0.f};
  #pragma unroll
  for (int ct = 0; ct < 8; ++ct)
    #pragma unroll
    for (int kt = 0; kt < 8; ++kt) {
      s16x4 b2 = *reinterpret_cast<const s16x4*>(&s_w2[(ct * 16 + c) * 136 + kt * 16 + g * 4]);
      #pragma unroll
      for (int mt = 0; mt < 2; ++mt)
        acc[ct][mt] = __builtin_amdgcn_mfma_f32_16x16x16bf16_1k(afr[mt][kt], b2, acc[ct][mt], 0, 0, 0);
    }

  #pragma unroll
  for (int ct = 0; ct < 8; ++ct) {
    const float bias = s_b2[ct * 16 + c];
    #pragma unroll
    for (int mt = 0; mt < 2; ++mt)
      #pragma unroll
      for (int q = 0; q < 4; ++q) {
        long row = base + mt * 16 + g * 4 + q;
        if (row < NN) out[row * HID + ct * 16 + c] = acc[ct][mt][q] + bias;
      }
  }
}

// ---------------------------------------------------------------- launch
extern "C" void kernel_launch(void* const* d_in, const int* in_sizes, int n_in,
                              void* d_out, int out_size, void* d_ws, size_t ws_size,
                              hipStream_t stream) {
  const float* node_repr = (const float*)d_in[0];
  const float* nbr_fea   = (const float*)d_in[1];
  const int*   nbr_idx   = (const int*)d_in[2];
  const float* fw1 = (const float*)d_in[3];
  const float* fb1 = (const float*)d_in[4];
  const float* fw2 = (const float*)d_in[5];
  const float* fb2 = (const float*)d_in[6];
  const float* uw1 = (const float*)d_in[7];
  const float* ub1 = (const float*)d_in[8];
  const float* uw2 = (const float*)d_in[9];
  const float* ub2 = (const float*)d_in[10];
  float* outp = (float*)d_out;
  short* ws16 = (short*)d_ws;
  // ws layout: [0, NN*HID) node_bf16 (later overwritten by u in k2a);
  //            then w1T (64*128 shorts), w2T (128*128 shorts)
  short* w1T = ws16 + (size_t)NN * HID;
  short* w2T = w1T + 64 * 128;

  k_cvt_node<<<(NN * HID / 4 + 255) / 256, 256, 0, stream>>>(node_repr, ws16);
  k_cvt_w<<<32, 256, 0, stream>>>(fw1, fw2, w1T, w2T);
  // k1: 1024 blocks x 256 thr (4 waves = 2 node-pairs), 4 blocks/CU target
  k_filter_message<<<1024, 256, 0, stream>>>(ws16, nbr_fea, nbr_idx,
                                             w1T, w2T, fb1, fb2, outp);
  const int rowblocks = (NN + 31) / 32;        // 1563
  const int grid2 = (rowblocks + 3) / 4;       // 391
  k_update1<<<grid2, 256, 0, stream>>>(outp, uw1, ub1, ws16);  // u overwrites node_bf16
  k_update2<<<grid2, 256, 0, stream>>>(ws16, uw2, ub2, outp);
}